// Round 3
// baseline (78.547 us; speedup 1.0000x reference)
//
#include <hip/hip_runtime.h>

#define HOP      512
#define NHARM    100
#define TFRAMES  400
#define INV_SR   (1.0f / 44100.0f)
#define INV_2PI  0.15915494309189535f

// cos(2*pi*t), t in revolutions (v_fract + v_cos).
__device__ __forceinline__ float cos_rev(float t) {
    return __builtin_amdgcn_cosf(__builtin_amdgcn_fractf(t));
}

// One 64-thread block per 1024-sample chunk-pair p: out [1024p, 1024p+1024).
// Sample r (local) gets: mid frame 2p+1 (x=r-512, all lanes) and outer frame
// (2p with x=r for lanes 0-31, 2p+2 with x=r-1024 for lanes 32-63).
// Shifts folded into staged phase so every role evaluates fr*r + ph.
// hann weights collapse to: out = 0.5*(1+c)*S_outer + 0.5*(1-c)*S_mid,
// c = cos(2*pi*r/1024).
// Chebyshev recurrence over each lane's 16 contiguous samples:
//   cos(t+(j+1)fr) = 2cos(fr)*cos(t+j*fr) - cos(t+(j-1)fr).
__global__ __launch_bounds__(64) void sinstack_kernel(
    const float* __restrict__ ampl,
    const float* __restrict__ phase,
    const float* __restrict__ f0,
    float* __restrict__ out)
{
    const int p   = blockIdx.x;   // 0..199
    const int b   = blockIdx.y;   // batch
    const int tid = threadIdx.x;  // 0..63

    // role k=0: frame 2p (shift 0) | k=1: frame 2p+1 (shift 512) | k=2: frame 2p+2 (shift 1024)
    // {ampl, fr (rev/sample), ph (rev, shift folded), 2*cos(2pi*fr)}
    __shared__ float4 sPar[3 * NHARM];

    for (int i = tid; i < 3 * NHARM; i += 64) {
        const int k = i / NHARM;
        const int n = i - k * NHARM;
        const int t = 2 * p + k;
        float4 par = make_float4(0.f, 0.f, 0.f, 2.f);
        if (t < TFRAMES) {
            const int idx = (b * NHARM + n) * TFRAMES + t;
            const float a  = ampl[idx];
            const float fr = f0[idx] * INV_SR;                       // rev/sample
            const float ph = phase[idx] * INV_2PI - (float)(512 * k) * fr;
            par = make_float4(a, fr, ph, 2.0f * cos_rev(fr));
        }
        sPar[i] = par;
    }
    __syncthreads();

    const float r0 = (float)(tid * 16);
    const float4* outPar = sPar + ((tid & 32) ? 2 * NHARM : 0);  // 2-addr LDS read: free
    const float4* midPar = sPar + NHARM;

    float aO[16], aM[16];
#pragma unroll
    for (int j = 0; j < 16; ++j) { aO[j] = 0.f; aM[j] = 0.f; }

#pragma unroll 2
    for (int n = 0; n < NHARM; ++n) {
        const float4 po = outPar[n];
        const float4 pm = midPar[n];
        const float to0 = fmaf(po.y, r0, po.z);
        const float tm0 = fmaf(pm.y, r0, pm.z);
        float oPrev = cos_rev(to0);
        float mPrev = cos_rev(tm0);
        float oCur  = cos_rev(to0 + po.y);
        float mCur  = cos_rev(tm0 + pm.y);
        aO[0] = fmaf(po.x, oPrev, aO[0]);
        aM[0] = fmaf(pm.x, mPrev, aM[0]);
        aO[1] = fmaf(po.x, oCur,  aO[1]);
        aM[1] = fmaf(pm.x, mCur,  aM[1]);
#pragma unroll
        for (int j = 2; j < 16; ++j) {
            const float oN = fmaf(po.w, oCur, -oPrev);
            const float mN = fmaf(pm.w, mCur, -mPrev);
            aO[j] = fmaf(po.x, oN, aO[j]);
            aM[j] = fmaf(pm.x, mN, aM[j]);
            oPrev = oCur; oCur = oN;
            mPrev = mCur; mCur = mN;
        }
    }

    float o[16];
#pragma unroll
    for (int j = 0; j < 16; ++j) {
        const float c = cos_rev((r0 + (float)j) * (1.0f / 1024.0f));
        o[j] = 0.5f * ((aO[j] + aM[j]) + c * (aO[j] - aM[j]));
    }

    float* op = out + ((size_t)b * (TFRAMES * HOP)) + (size_t)p * 1024 + tid * 16;
#pragma unroll
    for (int j = 0; j < 4; ++j)
        *(float4*)(op + 4 * j) = make_float4(o[4*j], o[4*j+1], o[4*j+2], o[4*j+3]);
}

extern "C" void kernel_launch(void* const* d_in, const int* in_sizes, int n_in,
                              void* d_out, int out_size, void* d_ws, size_t ws_size,
                              hipStream_t stream) {
    const float* ampl  = (const float*)d_in[0];
    const float* phase = (const float*)d_in[1];
    const float* f0    = (const float*)d_in[2];
    float* out = (float*)d_out;

    const int B = in_sizes[0] / (NHARM * TFRAMES);  // = 4
    dim3 grid(TFRAMES / 2, B);
    sinstack_kernel<<<grid, 64, 0, stream>>>(ampl, phase, f0, out);
}

// Round 4
// 74.929 us; speedup vs baseline: 1.0483x; 1.0483x over previous
//
#include <hip/hip_runtime.h>

#define HOP      512
#define NHARM    100
#define TFRAMES  400
#define INV_SR   (1.0f / 44100.0f)
#define INV_2PI  0.15915494309189535f

// cos(2*pi*t), t in revolutions (v_fract + v_cos).
__device__ __forceinline__ float cos_rev(float t) {
    return __builtin_amdgcn_cosf(__builtin_amdgcn_fractf(t));
}

// One 256-thread block (4 waves) per 1024-sample chunk-pair p.
// Sample r (local, 0..1023): mid frame 2p+1 (x=r-512, all lanes) and outer
// frame (2p with x=r for lanes<32, 2p+2 with x=r-1024 for lanes>=32);
// shifts folded into staged phase. hann collapses to
//   out = 0.5*(1+c)*S_outer + 0.5*(1-c)*S_mid,  c = cos(2*pi*r/1024).
// TLP fix vs round 3: harmonics split across the 4 waves (25 each); each
// wave computes a windowed partial over all 1024 samples (16/lane via
// Chebyshev recurrence), partials summed through LDS. 3200 waves total
// -> ~3-4 waves/SIMD hides the serial fma-chain + cos + LDS latencies.
__global__ __launch_bounds__(256) void sinstack_kernel(
    const float* __restrict__ ampl,
    const float* __restrict__ phase,
    const float* __restrict__ f0,
    float* __restrict__ out)
{
    const int p    = blockIdx.x;   // 0..199
    const int b    = blockIdx.y;   // batch
    const int tid  = threadIdx.x;  // 0..255
    const int wave = tid >> 6;     // 0..3
    const int lane = tid & 63;

    // role k=0: frame 2p (shift 0) | k=1: 2p+1 (shift 512) | k=2: 2p+2 (shift 1024)
    // {ampl, fr (rev/sample), ph (rev, shift folded), 2*cos(2pi*fr)}
    __shared__ float4 sPar[3 * NHARM];
    // windowed partials, transposed: sOut[w*1024 + j*64 + lane] (bank = lane%32, conflict-free)
    __shared__ float sOut[4 * 1024];

    for (int i = tid; i < 3 * NHARM; i += 256) {
        const int k = i / NHARM;
        const int n = i - k * NHARM;
        const int t = 2 * p + k;
        float4 par = make_float4(0.f, 0.f, 0.f, 2.f);
        if (t < TFRAMES) {
            const int idx = (b * NHARM + n) * TFRAMES + t;
            const float a  = ampl[idx];
            const float fr = f0[idx] * INV_SR;                       // rev/sample
            const float ph = phase[idx] * INV_2PI - (float)(512 * k) * fr;
            par = make_float4(a, fr, ph, 2.0f * cos_rev(fr));
        }
        sPar[i] = par;
    }
    __syncthreads();

    const float r0 = (float)(lane * 16);
    const float4* outPar = sPar + ((lane & 32) ? 2 * NHARM : 0);
    const float4* midPar = sPar + NHARM;
    const int n0 = 25 * wave;
    const int n1 = n0 + 25;

    float aO[16], aM[16];
#pragma unroll
    for (int j = 0; j < 16; ++j) { aO[j] = 0.f; aM[j] = 0.f; }

    // rotating register prefetch takes the LDS read off the critical path
    float4 po = outPar[n0];
    float4 pm = midPar[n0];
    for (int n = n0; n < n1; ++n) {
        const int nn = (n + 1 < n1) ? (n + 1) : n0;
        const float4 poN = outPar[nn];
        const float4 pmN = midPar[nn];

        const float to0 = fmaf(po.y, r0, po.z);
        const float tm0 = fmaf(pm.y, r0, pm.z);
        float oPrev = cos_rev(to0);
        float mPrev = cos_rev(tm0);
        float oCur  = cos_rev(to0 + po.y);
        float mCur  = cos_rev(tm0 + pm.y);
        aO[0] = fmaf(po.x, oPrev, aO[0]);
        aM[0] = fmaf(pm.x, mPrev, aM[0]);
        aO[1] = fmaf(po.x, oCur,  aO[1]);
        aM[1] = fmaf(pm.x, mCur,  aM[1]);
#pragma unroll
        for (int j = 2; j < 16; ++j) {
            const float oN = fmaf(po.w, oCur, -oPrev);
            const float mN = fmaf(pm.w, mCur, -mPrev);
            aO[j] = fmaf(po.x, oN, aO[j]);
            aM[j] = fmaf(pm.x, mN, aM[j]);
            oPrev = oCur; oCur = oN;
            mPrev = mCur; mCur = mN;
        }
        po = poN; pm = pmN;
    }

    // window (linear in partials -> apply per wave), transposed LDS write
    float* myOut = sOut + wave * 1024 + lane;
#pragma unroll
    for (int j = 0; j < 16; ++j) {
        const float c = cos_rev((r0 + (float)j) * (1.0f / 1024.0f));
        myOut[j * 64] = 0.5f * ((aO[j] + aM[j]) + c * (aO[j] - aM[j]));
    }
    __syncthreads();

    // reduce 4 partials; thread t -> samples 4t..4t+3, coalesced float4 store
    float4 v;
    float* vp = &v.x;
#pragma unroll
    for (int i = 0; i < 4; ++i) {
        const int s   = 4 * tid + i;
        const int pos = (s & 15) * 64 + (s >> 4);   // inverse of transposed layout
        vp[i] = sOut[pos] + sOut[1024 + pos] + sOut[2048 + pos] + sOut[3072 + pos];
    }
    *(float4*)(out + ((size_t)b * (TFRAMES * HOP)) + (size_t)p * 1024 + 4 * tid) = v;
}

extern "C" void kernel_launch(void* const* d_in, const int* in_sizes, int n_in,
                              void* d_out, int out_size, void* d_ws, size_t ws_size,
                              hipStream_t stream) {
    const float* ampl  = (const float*)d_in[0];
    const float* phase = (const float*)d_in[1];
    const float* f0    = (const float*)d_in[2];
    float* out = (float*)d_out;

    const int B = in_sizes[0] / (NHARM * TFRAMES);  // = 4
    dim3 grid(TFRAMES / 2, B);
    sinstack_kernel<<<grid, 256, 0, stream>>>(ampl, phase, f0, out);
}